// Round 6
// baseline (106.708 us; speedup 1.0000x reference)
//
#include <hip/hip_runtime.h>
#include <hip/hip_fp16.h>
#include <math.h>

#define BATCH 32
#define NPIX 160
#define LDIM 128
#define OUT_SZ 150        // 160 - 11 + 1

#define THREADS 512
// dual-tile blocks: each handles 2 of the 1824 (b,c,tile) items; + 1 KLD block
#define N_BLOCKS 913
// Per-sub-tile LDS region (float units; one __half2 = 4 B = ONE float slot):
//   HXY  [0,2880):  half2[18][160] staged pixels (x=img_in, y=img_out)
//   SCRATCH [2880,8960): union, sequential use:
//     stft RD:  [r 0..15][vv 0..4][pc 0..37] float2(re2,im2) = 6080 slots
//       (pc-fastest: consecutive-lane b64 accesses are contiguous -> conflict-free)
//     ssim VP:  VPMU half2[8][164] (mu_x,mu_y)   = 1312
//               VPVV half2[8][164] (E[xx],E[yy]) = 1312
//               VPXY float[8][164]  E[xy]        = 1312   (3936 <= 6080)
// Two regions per block: 17920 floats = 71.7 KB -> 2 blocks/CU.
// 5-phase structure amortized over 2 tiles: stage -> A -> B -> V -> H.
#define REGION   8960
#define RD_OFF   2880
#define VPMU_OFF 2880
#define VPVV_OFF 4192
#define VPXY_OFF 5504
#define VROWSTR  164

// e^{-i*2pi*k/12}; entries 0 / ±0.5 / ±0.866 / ±1
__device__ constexpr float TWC[12] = { 1.f, 0.86602540f, 0.5f, 0.f, -0.5f, -0.86602540f,
                                      -1.f,-0.86602540f,-0.5f, 0.f,  0.5f,  0.86602540f};
__device__ constexpr float TWS[12] = { 0.f,-0.5f,-0.86602540f,-1.f,-0.86602540f,-0.5f,
                                       0.f, 0.5f, 0.86602540f, 1.f, 0.86602540f, 0.5f};

__device__ constexpr float GW[11] = {0.00102838f, 0.00759876f, 0.03600076f, 0.10936070f,
                                     0.21300554f, 0.26601172f, 0.21300554f, 0.10936070f,
                                     0.03600076f, 0.00759876f, 0.00102838f};

// minimax atan poly, max err ~1e-6 rad (validated; rcp adds ~1ulp)
__device__ __forceinline__ float fast_atan2f(float y, float x) {
    float ax = fabsf(x), ay = fabsf(y);
    float mx = fmaxf(ax, ay), mn = fminf(ax, ay);
    float z = mn * __builtin_amdgcn_rcpf(mx);
    float z2 = z * z;
    float p = fmaf(z2, -0.01172120f, 0.05265332f);
    p = fmaf(z2, p, -0.11643287f);
    p = fmaf(z2, p, 0.19354346f);
    p = fmaf(z2, p, -0.33262347f);
    p = fmaf(z2, p, 0.99997726f);
    p = p * z;
    if (ay > ax) p = 1.57079632679489662f - p;
    if (x < 0.f) p = 3.14159265358979323f - p;
    return (y < 0.f) ? -p : p;
}

// swap the two halves of a __half2 (one v_alignbit_b32)
__device__ __forceinline__ __half2 h2swap(__half2 v) {
    unsigned u;
    __builtin_memcpy(&u, &v, 4);
    u = (u >> 16) | (u << 16);
    __half2 r;
    __builtin_memcpy(&r, &u, 4);
    return r;
}

// extract channel C of 4 consecutive NHWC pixels held in 3 float4s (wave-uniform c)
__device__ __forceinline__ float4 extract_c(float4 f0, float4 f1, float4 f2, int c) {
    if (c == 0) return make_float4(f0.x, f0.w, f1.z, f2.y);
    if (c == 1) return make_float4(f0.y, f1.x, f1.w, f2.z);
    return make_float4(f0.z, f1.y, f2.x, f2.w);
}

// ---- per-phase task bodies (called once per sub-tile; inlined, chains interleave) ----

__device__ __forceinline__ void stage_task(const float* __restrict__ xin,
                                           const float* __restrict__ xout,
                                           int b, int c, int r0,
                                           __half2* HXY, int t) {
    int rr = t / 40;
    int cq = t % 40;
    int row = r0 + rr;
    float4 xa = make_float4(0.f, 0.f, 0.f, 0.f);
    float4 xb = make_float4(0.f, 0.f, 0.f, 0.f);
    if (row < NPIX) {
        size_t off = ((size_t)(b * 160 + row) * 160 + cq * 4) * 3;
        const float4* qa = (const float4*)(xin + off);
        const float4* qb = (const float4*)(xout + off);
        float4 a0 = qa[0], a1 = qa[1], a2 = qa[2];
        float4 b0 = qb[0], b1 = qb[1], b2 = qb[2];
        xa = extract_c(a0, a1, a2, c);
        xb = extract_c(b0, b1, b2, c);
    }
    __half2 h[4] __attribute__((aligned(16)));
    h[0] = __floats2half2_rn(xa.x, xb.x);
    h[1] = __floats2half2_rn(xa.y, xb.y);
    h[2] = __floats2half2_rn(xa.z, xb.z);
    h[3] = __floats2half2_rn(xa.w, xb.w);
    *(float4*)&HXY[rr * 160 + cq * 4] = *(float4*)h;
}

__device__ __forceinline__ void adft_task(const __half2* HXY, __half2* RD, int t) {
    const __half2 hz = __float2half2_rn(0.f);
    int pc = t % 38;
    int r  = t / 38;
    float4 raw[3];
    raw[0] = *(const float4*)&HXY[r * 160 + pc * 4];
    raw[1] = *(const float4*)&HXY[r * 160 + pc * 4 + 4];
    raw[2] = *(const float4*)&HXY[r * 160 + pc * 4 + 8];
    const __half2* x = (const __half2*)raw;        // x[j] = (imgA, imgB)
    __half2 ev[5], ov[5];
    #pragma unroll
    for (int j = 1; j <= 5; ++j) {
        ev[j-1] = __hadd2(x[j], x[12 - j]);
        ov[j-1] = __hsub2(x[j], x[12 - j]);
    }
    #pragma unroll
    for (int vv = 0; vv < 5; ++vv) {
        const int v = vv + 1;
        __half2 re = (v & 1) ? __hsub2(x[0], x[6]) : __hadd2(x[0], x[6]);
        __half2 im = hz;
        #pragma unroll
        for (int j = 1; j <= 5; ++j) {
            const int kk = (v * j) % 12;           // compile-time
            re = __hfma2(ev[j-1], __float2half2_rn(TWC[kk]), re);
            im = __hfma2(ov[j-1], __float2half2_rn(TWS[kk]), im);
        }
        __half2 w2[2] __attribute__((aligned(8)));
        w2[0] = re;   // (reA, reB)
        w2[1] = im;   // (imA, imB)
        *(float2*)&RD[((r * 5 + vv) * 38 + pc) * 2] = *(float2*)w2;
    }
}

__device__ __forceinline__ float bdft_task(const __half2* RD, int tid_) {
    const __half2 hz = __float2half2_rn(0.f);
    int pc = tid_ % 38;
    int vv = (tid_ / 38) % 5;
    int g  = tid_ / 190;
    __half2 FR[5], FI[5];
    #pragma unroll
    for (int uu = 0; uu < 5; ++uu) { FR[uu] = hz; FI[uu] = hz; }
    #pragma unroll
    for (int i = 0; i < 6; ++i) {
        int rlo = 4 * g + i, rhi = rlo + 6;
        __half2 lo[2] __attribute__((aligned(8)));
        __half2 hi[2] __attribute__((aligned(8)));
        *(float2*)lo = *(const float2*)&RD[((rlo * 5 + vv) * 38 + pc) * 2];
        *(float2*)hi = *(const float2*)&RD[((rhi * 5 + vv) * 38 + pc) * 2];
        __half2 spR = __hadd2(lo[0], hi[0]), smR = __hsub2(lo[0], hi[0]);
        __half2 spI = __hadd2(lo[1], hi[1]), smI = __hsub2(lo[1], hi[1]);
        #pragma unroll
        for (int uu = 0; uu < 5; ++uu) {
            const int u = uu + 1;
            const int kk = (u * i) % 12;           // compile-time twiddle
            __half2 sR = (u & 1) ? smR : spR;
            __half2 sI = (u & 1) ? smI : spI;
            FR[uu] = __hfma2(sR, __float2half2_rn(TWC[kk]),
                     __hfma2(sI, __float2half2_rn(-TWS[kk]), FR[uu]));
            FI[uu] = __hfma2(sI, __float2half2_rn(TWC[kk]),
                     __hfma2(sR, __float2half2_rn(TWS[kk]), FI[uu]));
        }
    }
    float sacc = 0.f;
    #pragma unroll
    for (int uu = 0; uu < 5; ++uu) {
        float2 fr = __half22float2(FR[uu]);        // (A, B)
        float2 fi = __half22float2(FI[uu]);
        float aI = fast_atan2f(fi.x, fr.x + 1e-8f);
        float aO = fast_atan2f(fi.y, fr.y + 1e-8f);
        float mI = __builtin_amdgcn_sqrtf(fmaf(fr.x, fr.x, fi.x * fi.x));
        float mO = __builtin_amdgcn_sqrtf(fmaf(fr.y, fr.y, fi.y * fi.y));
        float ff = (float)((uu + 1) * (vv + 1)) * 0.04f;
        sacc += ff * (fabsf(aO - aI) + fabsf(mO - mI));
    }
    return sacc;
}

__device__ __forceinline__ void v_task(const __half2* HXY, float* SM, int t) {
    const __half2 hz = __float2half2_rn(0.f);
    int orow = t / 40;
    int cbase = (t % 40) * 4;
    __half2 amu[4], avv[4], axy[4];
    #pragma unroll
    for (int o = 0; o < 4; ++o) { amu[o] = hz; avv[o] = hz; axy[o] = hz; }
    #pragma unroll
    for (int kk = 0; kk < 11; ++kk) {
        float4 raw = *(const float4*)&HXY[(orow + kk) * 160 + cbase];
        const __half2* h = (const __half2*)&raw;
        const __half2 w2 = __float2half2_rn(GW[kk]);   // compile-time
        #pragma unroll
        for (int o = 0; o < 4; ++o) {
            __half2 t2 = __hmul2(w2, h[o]);            // (w*x, w*y)
            amu[o] = __hadd2(amu[o], t2);              // (mu_x, mu_y)
            avv[o] = __hfma2(t2, h[o], avv[o]);        // (E[xx], E[yy])
            axy[o] = __hfma2(t2, h2swap(h[o]), axy[o]);// lo lane = w*x*y
        }
    }
    int base = orow * VROWSTR + cbase;
    *(float4*)&SM[VPMU_OFF + base] = *(float4*)amu;
    *(float4*)&SM[VPVV_OFF + base] = *(float4*)avv;
    *(float4*)&SM[VPXY_OFF + base] = make_float4(
        __low2float(axy[0]), __low2float(axy[1]),
        __low2float(axy[2]), __low2float(axy[3]));
}

__device__ __forceinline__ float h_task(const float* SM, int r0, int t) {
    const __half2 hz = __float2half2_rn(0.f);
    int orow = t / 75;
    int oc = (t % 75) * 2;
    int base = orow * VROWSTR + oc;
    __half2 m[12], s0 = hz, s1 = hz;
    #pragma unroll
    for (int q = 0; q < 6; ++q)
        *(float2*)&m[2 * q] = *(const float2*)&SM[VPMU_OFF + base + 2 * q];
    #pragma unroll
    for (int kk = 0; kk < 11; ++kk) {
        const __half2 w2 = __float2half2_rn(GW[kk]);
        s0 = __hfma2(w2, m[kk],     s0);
        s1 = __hfma2(w2, m[kk + 1], s1);
    }
    float2 mu0 = __half22float2(s0);   // (mx, my) @ oc
    float2 mu1 = __half22float2(s1);   // (mx, my) @ oc+1
    __half2 v0 = hz, v1 = hz;
    #pragma unroll
    for (int q = 0; q < 6; ++q)
        *(float2*)&m[2 * q] = *(const float2*)&SM[VPVV_OFF + base + 2 * q];
    #pragma unroll
    for (int kk = 0; kk < 11; ++kk) {
        const __half2 w2 = __float2half2_rn(GW[kk]);
        v0 = __hfma2(w2, m[kk],     v0);
        v1 = __hfma2(w2, m[kk + 1], v1);
    }
    float2 vv0 = __half22float2(v0);   // (E[xx], E[yy]) @ oc
    float2 vv1 = __half22float2(v1);
    float zs[12];
    #pragma unroll
    for (int q = 0; q < 6; ++q) {
        float2 y2 = *(const float2*)&SM[VPXY_OFF + base + 2 * q];
        zs[2 * q] = y2.x; zs[2 * q + 1] = y2.y;
    }
    float xy0 = 0.f, xy1 = 0.f;
    #pragma unroll
    for (int kk = 0; kk < 11; ++kk) {
        xy0 = fmaf(GW[kk], zs[kk],     xy0);
        xy1 = fmaf(GW[kk], zs[kk + 1], xy1);
    }
    float hacc = 0.f;
    if (r0 + orow < OUT_SZ) {
        const float c1 = 1e-4f, c2 = 9e-4f;
        #pragma unroll
        for (int o = 0; o < 2; ++o) {
            float mx = o ? mu1.x : mu0.x, my = o ? mu1.y : mu0.y;
            float ex = o ? vv1.x : vv0.x, ey = o ? vv1.y : vv0.y;
            float cv = (o ? xy1 : xy0) - mx * my;
            float vx = ex - mx * mx;
            float vy = ey - my * my;
            float lum = (2.f * mx * my + c1) *
                        __builtin_amdgcn_rcpf(fmaf(mx, mx, my * my) + c1);
            float cs  = (2.f * cv + c2) *
                        __builtin_amdgcn_rcpf(vx + vy + c2);
            hacc += lum * cs;
        }
    }
    return hacc;
}

__global__ __launch_bounds__(THREADS, 4) void work_kernel(const float* __restrict__ xin,
                                                          const float* __restrict__ xout,
                                                          const float* __restrict__ mean,
                                                          const float* __restrict__ logvar,
                                                          float* __restrict__ out) {
    __shared__ __align__(16) float SMEM[2 * REGION];
    __shared__ float sm8[8];
    const int tid = threadIdx.x;
    const int gid = blockIdx.x;
    float acc = 0.f;

    if (gid == 912) {
        // ---- KLD block ----
        float a = 0.f;
        for (int i = tid; i < BATCH * LDIM; i += THREADS) {
            float m = mean[i], lv = logvar[i];
            a += -0.5f * (1.f + lv - expf(lv) - m * m) * (1.f / 32.f);
        }
        #pragma unroll
        for (int o = 32; o > 0; o >>= 1) a += __shfl_down(a, o, 64);
        if ((tid & 63) == 0) sm8[tid >> 6] = a;
        __syncthreads();
        if (tid == 0) {
            float s = sm8[0];
            #pragma unroll
            for (int i = 1; i < 8; ++i) s += sm8[i];
            atomicAdd(out, s);
        }
        return;
    }

    // XCD-aware chunking (912 = 8*114, bijective), then each block takes 2
    // consecutive items (c-fastest) -> sub-tiles usually share (b,tile): their
    // staging float4 loads hit the same cache lines (different channel extract).
    int idx = (gid & 7) * 114 + (gid >> 3);
    int i0 = idx * 2, i1 = i0 + 1;
    int b0 = i0 / 57, t0r = i0 % 57;
    int b1 = i1 / 57, t1r = i1 % 57;
    int c0 = t0r % 3, r0a = (t0r / 3) * 8;
    int c1 = t1r % 3, r0b = (t1r / 3) * 8;

    float* S0 = SMEM;
    float* S1 = SMEM + REGION;
    __half2* HXY0 = (__half2*)S0;
    __half2* HXY1 = (__half2*)S1;
    __half2* RD0  = (__half2*)(S0 + RD_OFF);
    __half2* RD1  = (__half2*)(S1 + RD_OFF);

    // ---- stage: 720 tasks x 2 tiles ----
    for (int t = tid; t < 720; t += THREADS) {
        stage_task(xin, xout, b0, c0, r0a, HXY0, t);
        stage_task(xin, xout, b1, c1, r0b, HXY1, t);
    }
    __syncthreads();

    // ---- stft phase A: 608 tasks x 2 tiles ----
    for (int t = tid; t < 608; t += THREADS) {
        adft_task(HXY0, RD0, t);
        adft_task(HXY1, RD1, t);
    }
    __syncthreads();

    // ---- stft phase B: 380 tasks x 2 tiles ----
    if (tid < 380) {
        float s = bdft_task(RD0, tid) + bdft_task(RD1, tid);
        acc += s * (1e-4f / 32.f);
    }
    __syncthreads();   // RD dead; VP planes reuse the scratch region

    // ---- ssim phase V: 320 tasks x 2 tiles ----
    for (int t = tid; t < 320; t += THREADS) {
        v_task(HXY0, S0, t);
        v_task(HXY1, S1, t);
    }
    __syncthreads();

    // ---- ssim phase H: 600 tasks x 2 tiles ----
    {
        float hacc = 0.f;
        for (int t = tid; t < 600; t += THREADS) {
            hacc += h_task(S0, r0a, t);
            hacc += h_task(S1, r0b, t);
        }
        acc += hacc * (1.f / (32.f * 150.f * 150.f * 3.f));
    }

    // ---- block reduce (8 waves) -> one device-scope atomic per block ----
    #pragma unroll
    for (int o = 32; o > 0; o >>= 1) acc += __shfl_down(acc, o, 64);
    if ((tid & 63) == 0) sm8[tid >> 6] = acc;
    __syncthreads();
    if (tid == 0) {
        float s = sm8[0];
        #pragma unroll
        for (int i = 1; i < 8; ++i) s += sm8[i];
        atomicAdd(out, s);
    }
}

extern "C" void kernel_launch(void* const* d_in, const int* in_sizes, int n_in,
                              void* d_out, int out_size, void* d_ws, size_t ws_size,
                              hipStream_t stream) {
    const float* mean   = (const float*)d_in[0];
    const float* logvar = (const float*)d_in[1];
    const float* xin    = (const float*)d_in[2];
    const float* xout   = (const float*)d_in[3];
    float* out = (float*)d_out;

    hipMemsetAsync(out, 0, sizeof(float), stream);   // graph-capturable memset node
    work_kernel<<<N_BLOCKS, THREADS, 0, stream>>>(xin, xout, mean, logvar, out);
}

// Round 8
// 106.164 us; speedup vs baseline: 1.0051x; 1.0051x over previous
//
#include <hip/hip_runtime.h>
#include <hip/hip_fp16.h>
#include <math.h>

#define BATCH 32
#define NPIX 160
#define LDIM 128
#define OUT_SZ 150        // 160 - 11 + 1

#define THREADS 512
// one block per (b, c, tile): 32*3*19 = 1824 work blocks + 1 KLD block
#define N_BLOCKS 1825

// LDS (float units; one __half2 = 4 B = ONE float slot):
//   HXY [0, 2952): half2[18][164] staged pixels; row stride 164 (656B = 16 mod 128
//                  -> r-groups rotate banks for phase A's r-major lane map)
//   per-wave scratch slices after HXY:
//     waves 0..5: 800 floats each (pc-slice of 5), waves 6,7: 640 (slice of 4)
//     A/B use it as RD[r][vv][pcl] float2(re2,im2) = 160*npcl slots
//     V/H overlay VP planes: mu half2[160] @0, vv half2[160] @160, xy f32[160] @320
//   Same wave writes VP only after its own B read RD -> in-order per-wave LDS,
//   NO barrier needed. Barriers: stage + final reduce only.
#define HXYSTR 164
#define HXY_SZ (18 * HXYSTR)                        // 2952
#define SMEM_FLOATS (HXY_SZ + 6 * 800 + 2 * 640)    // 9032 floats = 36.1 KB -> 4 blocks/CU
#define VP_MU 0
#define VP_VV 160
#define VP_XY 320

// e^{-i*2pi*k/12}; entries 0 / ±0.5 / ±0.866 / ±1
__device__ constexpr float TWC[12] = { 1.f, 0.86602540f, 0.5f, 0.f, -0.5f, -0.86602540f,
                                      -1.f,-0.86602540f,-0.5f, 0.f,  0.5f,  0.86602540f};
__device__ constexpr float TWS[12] = { 0.f,-0.5f,-0.86602540f,-1.f,-0.86602540f,-0.5f,
                                       0.f, 0.5f, 0.86602540f, 1.f, 0.86602540f, 0.5f};

__device__ constexpr float GW[11] = {0.00102838f, 0.00759876f, 0.03600076f, 0.10936070f,
                                     0.21300554f, 0.26601172f, 0.21300554f, 0.10936070f,
                                     0.03600076f, 0.00759876f, 0.00102838f};

// minimax atan poly, max err ~1e-6 rad (validated; rcp adds ~1ulp)
__device__ __forceinline__ float fast_atan2f(float y, float x) {
    float ax = fabsf(x), ay = fabsf(y);
    float mx = fmaxf(ax, ay), mn = fminf(ax, ay);
    float z = mn * __builtin_amdgcn_rcpf(mx);
    float z2 = z * z;
    float p = fmaf(z2, -0.01172120f, 0.05265332f);
    p = fmaf(z2, p, -0.11643287f);
    p = fmaf(z2, p, 0.19354346f);
    p = fmaf(z2, p, -0.33262347f);
    p = fmaf(z2, p, 0.99997726f);
    p = p * z;
    if (ay > ax) p = 1.57079632679489662f - p;
    if (x < 0.f) p = 3.14159265358979323f - p;
    return (y < 0.f) ? -p : p;
}

// swap the two halves of a __half2 (one v_alignbit_b32)
__device__ __forceinline__ __half2 h2swap(__half2 v) {
    unsigned u;
    __builtin_memcpy(&u, &v, 4);
    u = (u >> 16) | (u << 16);
    __half2 r;
    __builtin_memcpy(&r, &u, 4);
    return r;
}

// extract channel C of 4 consecutive NHWC pixels held in 3 float4s (wave-uniform c)
__device__ __forceinline__ float4 extract_c(float4 f0, float4 f1, float4 f2, int c) {
    if (c == 0) return make_float4(f0.x, f0.w, f1.z, f2.y);
    if (c == 1) return make_float4(f0.y, f1.x, f1.w, f2.z);
    return make_float4(f0.z, f1.y, f2.x, f2.w);
}

__global__ __launch_bounds__(THREADS) void work_kernel(const float* __restrict__ xin,
                                                       const float* __restrict__ xout,
                                                       const float* __restrict__ mean,
                                                       const float* __restrict__ logvar,
                                                       float* __restrict__ out) {
    __shared__ __align__(16) float SMEM[SMEM_FLOATS];
    __shared__ float sm8[8];
    const int tid = threadIdx.x;
    const int gid = blockIdx.x;
    float acc = 0.f;

    if (gid == 1824) {
        // ---- KLD block ----
        float a = 0.f;
        for (int i = tid; i < BATCH * LDIM; i += THREADS) {
            float m = mean[i], lv = logvar[i];
            a += -0.5f * (1.f + lv - expf(lv) - m * m) * (1.f / 32.f);
        }
        #pragma unroll
        for (int o = 32; o > 0; o >>= 1) a += __shfl_down(a, o, 64);
        if ((tid & 63) == 0) sm8[tid >> 6] = a;
        __syncthreads();
        if (tid == 0) {
            float s = sm8[0];
            #pragma unroll
            for (int i = 1; i < 8; ++i) s += sm8[i];
            atomicAdd(out, s);
        }
        return;
    }

    // XCD-aware decode (1824 = 8*228): each XCD gets a contiguous chunk,
    // c-fastest so channel-triplets of one (b,tile) share L2 lines.
    int idx  = (gid & 7) * 228 + (gid >> 3);
    int b    = idx / 57;
    int rem  = idx % 57;
    int tile = rem / 3;
    int c    = rem % 3;
    int r0 = tile * 8;

    __half2* HXY = (__half2*)SMEM;                 // [rr 0..17][HXYSTR] = (x, y)
    const int wid  = tid >> 6;
    const int lane = tid & 63;
    // per-wave stft pc-slice and scratch slice
    const int npcl = (wid < 6) ? 5 : 4;
    const int pc0  = (wid < 6) ? wid * 5 : 30 + (wid - 6) * 4;
    float*   WS  = SMEM + HXY_SZ + ((wid < 6) ? wid * 800 : 4800 + (wid - 6) * 640);
    __half2* RDW = (__half2*)WS;                   // [r][vv][pcl] x (re2,im2)
    const __half2 hz = __float2half2_rn(0.f);

    // ---- stage: 720 tasks global pool; NHWC both imgs, extract c, pack half2 ----
    for (int t = tid; t < 720; t += THREADS) {
        int rr = t / 40;
        int cq = t % 40;
        int row = r0 + rr;
        float4 xa = make_float4(0.f, 0.f, 0.f, 0.f);
        float4 xb = make_float4(0.f, 0.f, 0.f, 0.f);
        if (row < NPIX) {
            size_t off = ((size_t)(b * 160 + row) * 160 + cq * 4) * 3;
            const float4* qa = (const float4*)(xin + off);
            const float4* qb = (const float4*)(xout + off);
            float4 a0 = qa[0], a1 = qa[1], a2 = qa[2];
            float4 b0 = qb[0], b1 = qb[1], b2 = qb[2];
            xa = extract_c(a0, a1, a2, c);
            xb = extract_c(b0, b1, b2, c);
        }
        __half2 h[4] __attribute__((aligned(16)));
        h[0] = __floats2half2_rn(xa.x, xb.x);
        h[1] = __floats2half2_rn(xa.y, xb.y);
        h[2] = __floats2half2_rn(xa.z, xb.z);
        h[3] = __floats2half2_rn(xa.w, xb.w);
        *(float4*)&HXY[rr * HXYSTR + cq * 4] = *(float4*)h;
    }
    __syncthreads();   // the ONLY data barrier

    // ---- phase A (per wave): row-DFT for own pc-slice; 16*npcl tasks on 64 lanes ----
    for (int t = lane; t < 16 * npcl; t += 64) {
        int r, pcl;
        if (npcl == 5) { r = t / 5;  pcl = t - r * 5; }
        else           { r = t >> 2; pcl = t & 3; }
        int pc = pc0 + pcl;
        float4 raw[3];
        raw[0] = *(const float4*)&HXY[r * HXYSTR + pc * 4];
        raw[1] = *(const float4*)&HXY[r * HXYSTR + pc * 4 + 4];
        raw[2] = *(const float4*)&HXY[r * HXYSTR + pc * 4 + 8];
        const __half2* x = (const __half2*)raw;    // x[j] = (imgA, imgB)
        __half2 ev[5], ov[5];
        #pragma unroll
        for (int j = 1; j <= 5; ++j) {
            ev[j-1] = __hadd2(x[j], x[12 - j]);
            ov[j-1] = __hsub2(x[j], x[12 - j]);
        }
        #pragma unroll
        for (int vv = 0; vv < 5; ++vv) {
            const int v = vv + 1;
            __half2 re = (v & 1) ? __hsub2(x[0], x[6]) : __hadd2(x[0], x[6]);
            __half2 im = hz;
            #pragma unroll
            for (int j = 1; j <= 5; ++j) {
                const int kk = (v * j) % 12;       // compile-time
                re = __hfma2(ev[j-1], __float2half2_rn(TWC[kk]), re);
                im = __hfma2(ov[j-1], __float2half2_rn(TWS[kk]), im);
            }
            __half2 w2[2] __attribute__((aligned(8)));
            w2[0] = re;
            w2[1] = im;
            *(float2*)&RDW[((r * 5 + vv) * npcl + pcl) * 2] = *(float2*)w2;
        }
    }
    asm volatile("" ::: "memory");   // compiler fence (TBAA): keep A-writes before B-reads

    // ---- phase B (per wave): col-DFT + stft loss for own slice; 2*5*npcl lanes ----
    {
        int g = lane >> 5, j = lane & 31;
        if (j < 5 * npcl) {
            int vvq, pcl;
            if (npcl == 5) { vvq = j / 5;  pcl = j - vvq * 5; }
            else           { vvq = j >> 2; pcl = j & 3; }
            __half2 FR[5], FI[5];
            #pragma unroll
            for (int uu = 0; uu < 5; ++uu) { FR[uu] = hz; FI[uu] = hz; }
            #pragma unroll
            for (int i = 0; i < 6; ++i) {
                int rlo = 4 * g + i, rhi = rlo + 6;
                __half2 lo[2] __attribute__((aligned(8)));
                __half2 hi[2] __attribute__((aligned(8)));
                *(float2*)lo = *(const float2*)&RDW[((rlo * 5 + vvq) * npcl + pcl) * 2];
                *(float2*)hi = *(const float2*)&RDW[((rhi * 5 + vvq) * npcl + pcl) * 2];
                __half2 spR = __hadd2(lo[0], hi[0]), smR = __hsub2(lo[0], hi[0]);
                __half2 spI = __hadd2(lo[1], hi[1]), smI = __hsub2(lo[1], hi[1]);
                #pragma unroll
                for (int uu = 0; uu < 5; ++uu) {
                    const int u = uu + 1;
                    const int kk = (u * i) % 12;   // compile-time twiddle
                    __half2 sR = (u & 1) ? smR : spR;
                    __half2 sI = (u & 1) ? smI : spI;
                    FR[uu] = __hfma2(sR, __float2half2_rn(TWC[kk]),
                             __hfma2(sI, __float2half2_rn(-TWS[kk]), FR[uu]));
                    FI[uu] = __hfma2(sI, __float2half2_rn(TWC[kk]),
                             __hfma2(sR, __float2half2_rn(TWS[kk]), FI[uu]));
                }
            }
            float sacc = 0.f;
            #pragma unroll
            for (int uu = 0; uu < 5; ++uu) {
                float2 fr = __half22float2(FR[uu]);    // (in, out)
                float2 fi = __half22float2(FI[uu]);
                // |angle(out+eps) - angle(in+eps)| via one atan2 of out*conj(in):
                // wrapped w = atan2(Im, Re); raw-diff magnitude reconstructed from
                // the imag signs (cross-sign cases need the 2pi complement branch).
                float rb = fr.x + 1e-8f, ib = fi.x;    // in  (biased real)
                float ra = fr.y + 1e-8f, ia = fi.y;    // out
                float re_p = fmaf(ra, rb, ia * ib);
                float im_p = fmaf(ia, rb, -(ra * ib));
                float w  = fast_atan2f(im_p, re_p);
                float aw = fabsf(w);
                float alt = 6.28318530717958648f - aw;
                bool sa = (ia < 0.f), sb = (ib < 0.f);
                float adiff = (sa == sb) ? aw
                             : (((w >= 0.f) == !sa) ? aw : alt);
                float mI = __builtin_amdgcn_sqrtf(fmaf(fr.x, fr.x, fi.x * fi.x));
                float mO = __builtin_amdgcn_sqrtf(fmaf(fr.y, fr.y, fi.y * fi.y));
                float ff = (float)((uu + 1) * (vvq + 1)) * 0.04f;
                sacc += ff * (adiff + fabsf(mO - mI));
            }
            acc += sacc * (1e-4f / 32.f);
        }
    }
    asm volatile("" ::: "memory");   // keep B-reads (RD) before V-writes (VP overlay)

    // ---- phase V (per wave): vertical 11-tap for orow=wid; 40 lanes ----
    if (lane < 40) {
        const int orow = wid;
        int cbase = lane * 4;
        __half2 amu[4], avv[4], axy[4];
        #pragma unroll
        for (int o = 0; o < 4; ++o) { amu[o] = hz; avv[o] = hz; axy[o] = hz; }
        #pragma unroll
        for (int kk = 0; kk < 11; ++kk) {
            float4 raw = *(const float4*)&HXY[(orow + kk) * HXYSTR + cbase];
            const __half2* h = (const __half2*)&raw;
            const __half2 w2 = __float2half2_rn(GW[kk]);   // compile-time
            #pragma unroll
            for (int o = 0; o < 4; ++o) {
                __half2 t2 = __hmul2(w2, h[o]);            // (w*x, w*y)
                amu[o] = __hadd2(amu[o], t2);              // (mu_x, mu_y)
                avv[o] = __hfma2(t2, h[o], avv[o]);        // (E[xx], E[yy])
                axy[o] = __hfma2(t2, h2swap(h[o]), axy[o]);// lo lane = w*x*y
            }
        }
        *(float4*)&WS[VP_MU + cbase] = *(float4*)amu;
        *(float4*)&WS[VP_VV + cbase] = *(float4*)avv;
        *(float4*)&WS[VP_XY + cbase] = make_float4(
            __low2float(axy[0]), __low2float(axy[1]),
            __low2float(axy[2]), __low2float(axy[3]));
    }
    asm volatile("" ::: "memory");   // keep V-writes before H-reads

    // ---- phase H (per wave): horizontal conv + ssim for orow=wid; 75 tasks ----
    if (r0 + wid < OUT_SZ) {
        float hacc = 0.f;
        for (int t = lane; t < 75; t += 64) {
            int oc = t * 2;
            __half2 m[12], s0 = hz, s1 = hz;
            #pragma unroll
            for (int q = 0; q < 6; ++q)
                *(float2*)&m[2 * q] = *(const float2*)&WS[VP_MU + oc + 2 * q];
            #pragma unroll
            for (int kk = 0; kk < 11; ++kk) {
                const __half2 w2 = __float2half2_rn(GW[kk]);
                s0 = __hfma2(w2, m[kk],     s0);
                s1 = __hfma2(w2, m[kk + 1], s1);
            }
            float2 mu0 = __half22float2(s0);
            float2 mu1 = __half22float2(s1);
            __half2 v0 = hz, v1 = hz;
            #pragma unroll
            for (int q = 0; q < 6; ++q)
                *(float2*)&m[2 * q] = *(const float2*)&WS[VP_VV + oc + 2 * q];
            #pragma unroll
            for (int kk = 0; kk < 11; ++kk) {
                const __half2 w2 = __float2half2_rn(GW[kk]);
                v0 = __hfma2(w2, m[kk],     v0);
                v1 = __hfma2(w2, m[kk + 1], v1);
            }
            float2 vv0 = __half22float2(v0);
            float2 vv1 = __half22float2(v1);
            float zs[12];
            #pragma unroll
            for (int q = 0; q < 6; ++q) {
                float2 y2 = *(const float2*)&WS[VP_XY + oc + 2 * q];
                zs[2 * q] = y2.x; zs[2 * q + 1] = y2.y;
            }
            float xy0 = 0.f, xy1 = 0.f;
            #pragma unroll
            for (int kk = 0; kk < 11; ++kk) {
                xy0 = fmaf(GW[kk], zs[kk],     xy0);
                xy1 = fmaf(GW[kk], zs[kk + 1], xy1);
            }
            const float c1 = 1e-4f, c2 = 9e-4f;
            #pragma unroll
            for (int o = 0; o < 2; ++o) {
                float mx = o ? mu1.x : mu0.x, my = o ? mu1.y : mu0.y;
                float ex = o ? vv1.x : vv0.x, ey = o ? vv1.y : vv0.y;
                float cv = (o ? xy1 : xy0) - mx * my;
                float vx = ex - mx * mx;
                float vy = ey - my * my;
                float lum = (2.f * mx * my + c1) *
                            __builtin_amdgcn_rcpf(fmaf(mx, mx, my * my) + c1);
                float cs  = (2.f * cv + c2) *
                            __builtin_amdgcn_rcpf(vx + vy + c2);
                hacc += lum * cs;
            }
        }
        acc += hacc * (1.f / (32.f * 150.f * 150.f * 3.f));
    }

    // ---- block reduce (8 waves) -> one device-scope atomic per block ----
    #pragma unroll
    for (int o = 32; o > 0; o >>= 1) acc += __shfl_down(acc, o, 64);
    if ((tid & 63) == 0) sm8[tid >> 6] = acc;
    __syncthreads();
    if (tid == 0) {
        float s = sm8[0];
        #pragma unroll
        for (int i = 1; i < 8; ++i) s += sm8[i];
        atomicAdd(out, s);
    }
}

extern "C" void kernel_launch(void* const* d_in, const int* in_sizes, int n_in,
                              void* d_out, int out_size, void* d_ws, size_t ws_size,
                              hipStream_t stream) {
    const float* mean   = (const float*)d_in[0];
    const float* logvar = (const float*)d_in[1];
    const float* xin    = (const float*)d_in[2];
    const float* xout   = (const float*)d_in[3];
    float* out = (float*)d_out;

    hipMemsetAsync(out, 0, sizeof(float), stream);   // graph-capturable memset node
    work_kernel<<<N_BLOCKS, THREADS, 0, stream>>>(xin, xout, mean, logvar, out);
}

// Round 9
// 105.088 us; speedup vs baseline: 1.0154x; 1.0102x over previous
//
#include <hip/hip_runtime.h>
#include <hip/hip_fp16.h>
#include <math.h>

#define BATCH 32
#define NPIX 160
#define LDIM 128
#define OUT_SZ 150        // 160 - 11 + 1

#define THREADS 512
// one fused block per (b, c, tile): 32*3*19 = 1824 work blocks + 1 KLD block
#define N_BLOCKS 1825
// LDS carve (float units; one __half2 = 4 B = ONE float slot):
//   HXY  [0,2880):  half2[18][160] staged pixels (x=img_in, y=img_out)
//   SCRATCH [2880,8960): union region, sequential use:
//     stft RD:  [r 0..15][pc 0..37][vv 0..4][re2,im2] = 6080 slots (phases A,B)
//     ssim VP (phases V,H), row stride 166 (even: b64-aligned; 166%32=6 ->
//       orow-fastest H lanes land ~2-way on banks):
//       VPMU half2[8][166] (mu_x,mu_y)   @2880..4208
//       VPVV half2[8][166] (E[xx],E[yy]) @4208..5536
//       VPXY float[8][166]  E[xy]        @5536..6864   (<= 8960 ok)
// 5-phase pooled structure: stage -> A -> B -> V -> H (R5 skeleton; R6/R8 proved
// barrier count & ILP neutral -- the binding pipe is LDS, so V/H are coarsened
// to amortize overlapping window reads: V 2-orow/2-col, H 4-window tasks).
#define RD_OFF   2880
#define VPMU_OFF 2880
#define VPVV_OFF 4208
#define VPXY_OFF 5536
#define VROWSTR  166
#define SMEM_FLOATS 8960   // 35.8 KB -> 4 blocks/CU

// e^{-i*2pi*k/12}; entries 0 / ±0.5 / ±0.866 / ±1
__device__ constexpr float TWC[12] = { 1.f, 0.86602540f, 0.5f, 0.f, -0.5f, -0.86602540f,
                                      -1.f,-0.86602540f,-0.5f, 0.f,  0.5f,  0.86602540f};
__device__ constexpr float TWS[12] = { 0.f,-0.5f,-0.86602540f,-1.f,-0.86602540f,-0.5f,
                                       0.f, 0.5f, 0.86602540f, 1.f, 0.86602540f, 0.5f};

__device__ constexpr float GW[11] = {0.00102838f, 0.00759876f, 0.03600076f, 0.10936070f,
                                     0.21300554f, 0.26601172f, 0.21300554f, 0.10936070f,
                                     0.03600076f, 0.00759876f, 0.00102838f};

// minimax atan poly, max err ~1e-6 rad (validated; rcp adds ~1ulp)
__device__ __forceinline__ float fast_atan2f(float y, float x) {
    float ax = fabsf(x), ay = fabsf(y);
    float mx = fmaxf(ax, ay), mn = fminf(ax, ay);
    float z = mn * __builtin_amdgcn_rcpf(mx);
    float z2 = z * z;
    float p = fmaf(z2, -0.01172120f, 0.05265332f);
    p = fmaf(z2, p, -0.11643287f);
    p = fmaf(z2, p, 0.19354346f);
    p = fmaf(z2, p, -0.33262347f);
    p = fmaf(z2, p, 0.99997726f);
    p = p * z;
    if (ay > ax) p = 1.57079632679489662f - p;
    if (x < 0.f) p = 3.14159265358979323f - p;
    return (y < 0.f) ? -p : p;
}

// swap the two halves of a __half2 (one v_alignbit_b32)
__device__ __forceinline__ __half2 h2swap(__half2 v) {
    unsigned u;
    __builtin_memcpy(&u, &v, 4);
    u = (u >> 16) | (u << 16);
    __half2 r;
    __builtin_memcpy(&r, &u, 4);
    return r;
}

// extract channel C of 4 consecutive NHWC pixels held in 3 float4s (wave-uniform c)
__device__ __forceinline__ float4 extract_c(float4 f0, float4 f1, float4 f2, int c) {
    if (c == 0) return make_float4(f0.x, f0.w, f1.z, f2.y);
    if (c == 1) return make_float4(f0.y, f1.x, f1.w, f2.z);
    return make_float4(f0.z, f1.y, f2.x, f2.w);
}

__global__ __launch_bounds__(THREADS) void work_kernel(const float* __restrict__ xin,
                                                       const float* __restrict__ xout,
                                                       const float* __restrict__ mean,
                                                       const float* __restrict__ logvar,
                                                       float* __restrict__ out) {
    __shared__ __align__(16) float SMEM[SMEM_FLOATS];
    __shared__ float sm8[8];
    const int tid = threadIdx.x;
    const int gid = blockIdx.x;
    float acc = 0.f;

    if (gid == 1824) {
        // ---- KLD block ----
        float a = 0.f;
        for (int i = tid; i < BATCH * LDIM; i += THREADS) {
            float m = mean[i], lv = logvar[i];
            a += -0.5f * (1.f + lv - expf(lv) - m * m) * (1.f / 32.f);
        }
        #pragma unroll
        for (int o = 32; o > 0; o >>= 1) a += __shfl_down(a, o, 64);
        if ((tid & 63) == 0) sm8[tid >> 6] = a;
        __syncthreads();
        if (tid == 0) {
            float s = sm8[0];
            #pragma unroll
            for (int i = 1; i < 8; ++i) s += sm8[i];
            atomicAdd(out, s);
        }
        return;
    }

    // XCD-aware decode (1824 = 8*228): each XCD gets a contiguous chunk,
    // c-fastest so channel-triplets of one (b,tile) share L2 lines.
    int idx  = (gid & 7) * 228 + (gid >> 3);
    int b    = idx / 57;
    int rem  = idx % 57;
    int tile = rem / 3;
    int c    = rem % 3;
    int r0 = tile * 8;
    __half2* HXY = (__half2*)SMEM;                 // [rr 0..17][160] = (x, y)
    __half2* RD  = (__half2*)(SMEM + RD_OFF);      // stft scratch [r][pc][vv][re2,im2]
    const __half2 hz = __float2half2_rn(0.f);

    // ---- stage: 720 tasks (rr, colq); NHWC both imgs, extract c, pack half2 ----
    for (int t = tid; t < 720; t += THREADS) {
        int rr = t / 40;
        int cq = t % 40;
        int row = r0 + rr;
        float4 xa = make_float4(0.f, 0.f, 0.f, 0.f);
        float4 xb = make_float4(0.f, 0.f, 0.f, 0.f);
        if (row < NPIX) {
            size_t off = ((size_t)(b * 160 + row) * 160 + cq * 4) * 3;
            const float4* qa = (const float4*)(xin + off);
            const float4* qb = (const float4*)(xout + off);
            float4 a0 = qa[0], a1 = qa[1], a2 = qa[2];
            float4 b0 = qb[0], b1 = qb[1], b2 = qb[2];
            xa = extract_c(a0, a1, a2, c);
            xb = extract_c(b0, b1, b2, c);
        }
        __half2 h[4] __attribute__((aligned(16)));
        h[0] = __floats2half2_rn(xa.x, xb.x);
        h[1] = __floats2half2_rn(xa.y, xb.y);
        h[2] = __floats2half2_rn(xa.z, xb.z);
        h[3] = __floats2half2_rn(xa.w, xb.w);
        *(float4*)&HXY[rr * 160 + cq * 4] = *(float4*)h;
    }
    __syncthreads();

    // ---- stft phase A: 608 tasks (r 0..15, pc); packed-half DFT over BOTH imgs ----
    for (int t = tid; t < 608; t += THREADS) {
        int pc = t % 38;
        int r  = t / 38;
        float4 raw[3];
        raw[0] = *(const float4*)&HXY[r * 160 + pc * 4];
        raw[1] = *(const float4*)&HXY[r * 160 + pc * 4 + 4];
        raw[2] = *(const float4*)&HXY[r * 160 + pc * 4 + 8];
        const __half2* x = (const __half2*)raw;    // x[j] = (imgA, imgB)
        __half2 ev[5], ov[5];
        #pragma unroll
        for (int j = 1; j <= 5; ++j) {
            ev[j-1] = __hadd2(x[j], x[12 - j]);
            ov[j-1] = __hsub2(x[j], x[12 - j]);
        }
        __half2* dst = &RD[(r * 38 + pc) * 10];    // 10 consecutive slots
        #pragma unroll
        for (int vv = 0; vv < 5; ++vv) {
            const int v = vv + 1;
            __half2 re = (v & 1) ? __hsub2(x[0], x[6]) : __hadd2(x[0], x[6]);
            __half2 im = hz;
            #pragma unroll
            for (int j = 1; j <= 5; ++j) {
                const int kk = (v * j) % 12;       // compile-time
                re = __hfma2(ev[j-1], __float2half2_rn(TWC[kk]), re);
                im = __hfma2(ov[j-1], __float2half2_rn(TWS[kk]), im);
            }
            __half2 w2[2] __attribute__((aligned(8)));
            w2[0] = re;   // (reA, reB)
            w2[1] = im;   // (imA, imB)
            *(float2*)&dst[vv * 2] = *(float2*)w2;
        }
    }
    __syncthreads();

    // ---- stft phase B: 380 tasks (g, vv, pc); packed-half col-fold, fp32 epilogue ----
    if (tid < 380) {
        int pc = tid % 38;
        int vv = (tid / 38) % 5;
        int g  = tid / 190;
        __half2 FR[5], FI[5];
        #pragma unroll
        for (int uu = 0; uu < 5; ++uu) { FR[uu] = hz; FI[uu] = hz; }
        #pragma unroll
        for (int i = 0; i < 6; ++i) {
            int rlo = 4 * g + i, rhi = rlo + 6;
            __half2 lo[2] __attribute__((aligned(8)));
            __half2 hi[2] __attribute__((aligned(8)));
            *(float2*)lo = *(const float2*)&RD[(rlo * 38 + pc) * 10 + vv * 2];
            *(float2*)hi = *(const float2*)&RD[(rhi * 38 + pc) * 10 + vv * 2];
            __half2 spR = __hadd2(lo[0], hi[0]), smR = __hsub2(lo[0], hi[0]);
            __half2 spI = __hadd2(lo[1], hi[1]), smI = __hsub2(lo[1], hi[1]);
            #pragma unroll
            for (int uu = 0; uu < 5; ++uu) {
                const int u = uu + 1;
                const int kk = (u * i) % 12;       // compile-time twiddle
                __half2 sR = (u & 1) ? smR : spR;
                __half2 sI = (u & 1) ? smI : spI;
                FR[uu] = __hfma2(sR, __float2half2_rn(TWC[kk]),
                         __hfma2(sI, __float2half2_rn(-TWS[kk]), FR[uu]));
                FI[uu] = __hfma2(sI, __float2half2_rn(TWC[kk]),
                         __hfma2(sR, __float2half2_rn(TWS[kk]), FI[uu]));
            }
        }
        float sacc = 0.f;
        #pragma unroll
        for (int uu = 0; uu < 5; ++uu) {
            float2 fr = __half22float2(FR[uu]);    // (A, B)
            float2 fi = __half22float2(FI[uu]);
            float aI = fast_atan2f(fi.x, fr.x + 1e-8f);
            float aO = fast_atan2f(fi.y, fr.y + 1e-8f);
            float mI = __builtin_amdgcn_sqrtf(fmaf(fr.x, fr.x, fi.x * fi.x));
            float mO = __builtin_amdgcn_sqrtf(fmaf(fr.y, fr.y, fi.y * fi.y));
            float ff = (float)((uu + 1) * (vv + 1)) * 0.04f;
            sacc += ff * (fabsf(aO - aI) + fabsf(mO - mI));
        }
        acc += sacc * (1e-4f / 32.f);
    }
    __syncthreads();   // RD dead; VP planes reuse the scratch region

    // ---- ssim phase V: 320 tasks = (orow-pair 0..3) x (col-pair 0..79) ----
    // 12 shared b64 row-loads serve 2 orows' 11-tap sums (22 tap-uses):
    // halves V's LDS bytes vs 1-orow/4-col b128 version.
    for (int t = tid; t < 320; t += THREADS) {
        int op  = t / 80;          // orow pair: orows 2op, 2op+1
        int cp  = t % 80;          // column pair: cols 2cp, 2cp+1
        int col = cp * 2;
        __half2 amu[2][2], avv[2][2], axy[2][2];
        #pragma unroll
        for (int dr = 0; dr < 2; ++dr)
            #pragma unroll
            for (int o = 0; o < 2; ++o) { amu[dr][o] = hz; avv[dr][o] = hz; axy[dr][o] = hz; }
        #pragma unroll
        for (int kk = 0; kk < 12; ++kk) {
            __half2 h2[2] __attribute__((aligned(8)));
            *(float2*)h2 = *(const float2*)&HXY[(2 * op + kk) * 160 + col];
            if (kk < 11) {                         // orow0 taps 0..10
                const __half2 w2 = __float2half2_rn(GW[kk]);
                #pragma unroll
                for (int o = 0; o < 2; ++o) {
                    __half2 t2 = __hmul2(w2, h2[o]);
                    amu[0][o] = __hadd2(amu[0][o], t2);
                    avv[0][o] = __hfma2(t2, h2[o], avv[0][o]);
                    axy[0][o] = __hfma2(t2, h2swap(h2[o]), axy[0][o]);
                }
            }
            if (kk >= 1) {                         // orow1 taps 0..10 (rows 1..11)
                const __half2 w2 = __float2half2_rn(GW[kk - 1]);
                #pragma unroll
                for (int o = 0; o < 2; ++o) {
                    __half2 t2 = __hmul2(w2, h2[o]);
                    amu[1][o] = __hadd2(amu[1][o], t2);
                    avv[1][o] = __hfma2(t2, h2[o], avv[1][o]);
                    axy[1][o] = __hfma2(t2, h2swap(h2[o]), axy[1][o]);
                }
            }
        }
        #pragma unroll
        for (int dr = 0; dr < 2; ++dr) {
            int base = (2 * op + dr) * VROWSTR + col;
            __half2 pm[2] __attribute__((aligned(8)));
            __half2 pv[2] __attribute__((aligned(8)));
            pm[0] = amu[dr][0]; pm[1] = amu[dr][1];
            pv[0] = avv[dr][0]; pv[1] = avv[dr][1];
            *(float2*)&SMEM[VPMU_OFF + base] = *(float2*)pm;
            *(float2*)&SMEM[VPVV_OFF + base] = *(float2*)pv;
            *(float2*)&SMEM[VPXY_OFF + base] = make_float2(
                __low2float(axy[dr][0]), __low2float(axy[dr][1]));
        }
    }
    __syncthreads();

    // ---- ssim phase H: 304 tasks = (wgrp 0..37) x (orow 0..7); 4 windows/task ----
    // 14 plane values (7 b64) serve 4 sliding windows: -41% LDS bytes vs 2-window.
    // orow-fastest lanes + stride 166 -> ~2-way banks.
    {
        float hacc = 0.f;
        for (int t = tid; t < 304; t += THREADS) {
            int orow = t & 7;
            int wgrp = t >> 3;
            int w0 = wgrp * 4;
            int rbase = orow * VROWSTR + w0;
            __half2 mv[14];
            // mu plane
            #pragma unroll
            for (int q = 0; q < 7; ++q)
                *(float2*)&mv[2 * q] = *(const float2*)&SMEM[VPMU_OFF + rbase + 2 * q];
            __half2 ms[4];
            #pragma unroll
            for (int k = 0; k < 4; ++k) {
                __half2 s = hz;
                #pragma unroll
                for (int j = 0; j < 11; ++j)
                    s = __hfma2(__float2half2_rn(GW[j]), mv[k + j], s);
                ms[k] = s;
            }
            // vv plane
            #pragma unroll
            for (int q = 0; q < 7; ++q)
                *(float2*)&mv[2 * q] = *(const float2*)&SMEM[VPVV_OFF + rbase + 2 * q];
            __half2 vs[4];
            #pragma unroll
            for (int k = 0; k < 4; ++k) {
                __half2 s = hz;
                #pragma unroll
                for (int j = 0; j < 11; ++j)
                    s = __hfma2(__float2half2_rn(GW[j]), mv[k + j], s);
                vs[k] = s;
            }
            // xy plane (fp32)
            float xv[14];
            #pragma unroll
            for (int q = 0; q < 7; ++q) {
                float2 y2 = *(const float2*)&SMEM[VPXY_OFF + rbase + 2 * q];
                xv[2 * q] = y2.x; xv[2 * q + 1] = y2.y;
            }
            float xs[4];
            #pragma unroll
            for (int k = 0; k < 4; ++k) {
                float s = 0.f;
                #pragma unroll
                for (int j = 0; j < 11; ++j)
                    s = fmaf(GW[j], xv[k + j], s);
                xs[k] = s;
            }
            if (r0 + orow < OUT_SZ) {
                const float c1 = 1e-4f, c2 = 9e-4f;
                #pragma unroll
                for (int k = 0; k < 4; ++k) {
                    if (w0 + k < OUT_SZ) {
                        float2 mu = __half22float2(ms[k]);
                        float2 v2 = __half22float2(vs[k]);
                        float cv = xs[k] - mu.x * mu.y;
                        float vx = v2.x - mu.x * mu.x;
                        float vy = v2.y - mu.y * mu.y;
                        float lum = (2.f * mu.x * mu.y + c1) *
                                    __builtin_amdgcn_rcpf(fmaf(mu.x, mu.x, mu.y * mu.y) + c1);
                        float cs  = (2.f * cv + c2) *
                                    __builtin_amdgcn_rcpf(vx + vy + c2);
                        hacc += lum * cs;
                    }
                }
            }
        }
        acc += hacc * (1.f / (32.f * 150.f * 150.f * 3.f));
    }

    // ---- block reduce (8 waves) -> one device-scope atomic per block ----
    #pragma unroll
    for (int o = 32; o > 0; o >>= 1) acc += __shfl_down(acc, o, 64);
    if ((tid & 63) == 0) sm8[tid >> 6] = acc;
    __syncthreads();
    if (tid == 0) {
        float s = sm8[0];
        #pragma unroll
        for (int i = 1; i < 8; ++i) s += sm8[i];
        atomicAdd(out, s);
    }
}

extern "C" void kernel_launch(void* const* d_in, const int* in_sizes, int n_in,
                              void* d_out, int out_size, void* d_ws, size_t ws_size,
                              hipStream_t stream) {
    const float* mean   = (const float*)d_in[0];
    const float* logvar = (const float*)d_in[1];
    const float* xin    = (const float*)d_in[2];
    const float* xout   = (const float*)d_in[3];
    float* out = (float*)d_out;

    hipMemsetAsync(out, 0, sizeof(float), stream);   // graph-capturable memset node
    work_kernel<<<N_BLOCKS, THREADS, 0, stream>>>(xin, xout, mean, logvar, out);
}